// Round 1
// baseline (570.956 us; speedup 1.0000x reference)
//
#include <hip/hip_runtime.h>

// LSTM: B=1024, T=512, F=40, H=50, gates G=4H=200, fp32.
// One block per batch element; 512 sequential steps inside the block.
// Gate-row weights live in per-thread registers (thread g owns row g of
// W_ih and W_hh). x_t double-buffered in LDS with prefetch by idle lanes.

constexpr int kB = 1024;
constexpr int kT = 512;
constexpr int kF = 40;
constexpr int kH = 50;
constexpr int kG = 200;  // 4*H

__device__ __forceinline__ float fast_sigmoid(float v) {
    return __builtin_amdgcn_rcpf(1.f + __expf(-v));
}
__device__ __forceinline__ float fast_tanh(float v) {
    return 1.f - 2.f * __builtin_amdgcn_rcpf(__expf(2.f * v) + 1.f);
}

__global__ __launch_bounds__(256, 4) void lstm_fused(
    const float* __restrict__ x,      // [B,T,F]
    const float* __restrict__ W_ih,   // [G,F]
    const float* __restrict__ W_hh,   // [G,H]
    const float* __restrict__ b_ih,   // [G]
    const float* __restrict__ b_hh,   // [G]
    const float* __restrict__ W1,     // [10,H]
    const float* __restrict__ b1,     // [10]
    const float* __restrict__ W2,     // [1,10]
    const float* __restrict__ b2,     // [1]
    float* __restrict__ out)          // [B]
{
    const int b   = blockIdx.x;
    const int tid = threadIdx.x;

    __shared__ __align__(16) float sh_h[52];      // h state, padded to 13*float4
    __shared__ __align__(16) float sh_x[2][40];   // double-buffered x_t
    __shared__ __align__(16) float sh_pre[kG];    // gate pre-activations
    __shared__ float sh_head[10];

    // Per-thread weight registers: thread g holds W_ih[g,:] and W_hh[g,:].
    float wih[kF];
    float whh[52];
    float bias = 0.f;

    const float* __restrict__ xb = x + (size_t)b * kT * kF;

    if (tid < kG) {
#pragma unroll
        for (int k = 0; k < kF; ++k) wih[k] = W_ih[tid * kF + k];
#pragma unroll
        for (int k = 0; k < kH; ++k) whh[k] = W_hh[tid * kH + k];
        whh[50] = 0.f;
        whh[51] = 0.f;
        bias = b_ih[tid] + b_hh[tid];
    }

    // init states: h0 = 0; c0 = 0 except c0[:,0] = 1
    if (tid < 52) sh_h[tid] = 0.f;
    float c = (tid == 0) ? 1.f : 0.f;

    // stage x[b,0,:]
    if (tid < 10) {
        ((float4*)sh_x[0])[tid] = ((const float4*)xb)[tid];
    }
    __syncthreads();

    float4 px = make_float4(0.f, 0.f, 0.f, 0.f);

    for (int t = 0; t < kT; ++t) {
        const int cur = t & 1;

        // prefetch x[b,t+1,:] into registers (lanes 200..209, wave 3)
        if (tid >= 200 && tid < 210 && (t + 1) < kT) {
            px = ((const float4*)(xb + (size_t)(t + 1) * kF))[tid - 200];
        }

        if (tid < kG) {
            float acc = bias;
            const float4* xv = (const float4*)sh_x[cur];
#pragma unroll
            for (int q = 0; q < 10; ++q) {          // F = 40 = 10*4
                float4 v = xv[q];                    // broadcast LDS read
                acc = fmaf(v.x, wih[4*q+0], acc);
                acc = fmaf(v.y, wih[4*q+1], acc);
                acc = fmaf(v.z, wih[4*q+2], acc);
                acc = fmaf(v.w, wih[4*q+3], acc);
            }
            const float4* hv = (const float4*)sh_h;
#pragma unroll
            for (int q = 0; q < 13; ++q) {          // H padded to 52 = 13*4
                float4 v = hv[q];                    // broadcast LDS read
                acc = fmaf(v.x, whh[4*q+0], acc);
                acc = fmaf(v.y, whh[4*q+1], acc);
                acc = fmaf(v.z, whh[4*q+2], acc);
                acc = fmaf(v.w, whh[4*q+3], acc);
            }
            sh_pre[tid] = acc;
        }
        __syncthreads();

        // cell update: thread j < 50 owns hidden unit j (c stays in register)
        if (tid < kH) {
            float gi = sh_pre[tid];
            float gf = sh_pre[tid + kH];
            float gg = sh_pre[tid + 2 * kH];
            float go = sh_pre[tid + 3 * kH];
            float i_s = fast_sigmoid(gi);
            float f_s = fast_sigmoid(gf);
            float o_s = fast_sigmoid(go);
            float g_t = fast_tanh(gg);
            c = fmaf(f_s, c, i_s * g_t);
            sh_h[tid] = o_s * fast_tanh(c);
        }
        // commit prefetched x into the other buffer
        if (tid >= 200 && tid < 210 && (t + 1) < kT) {
            ((float4*)sh_x[cur ^ 1])[tid - 200] = px;
        }
        __syncthreads();
    }

    // head: relu(h @ W1.T + b1) @ W2.T + b2 + x[b, T-1, 0]
    if (tid < 10) {
        float acc = b1[tid];
#pragma unroll
        for (int k = 0; k < kH; ++k) acc = fmaf(sh_h[k], W1[tid * kH + k], acc);
        sh_head[tid] = fmaxf(acc, 0.f);
    }
    __syncthreads();
    if (tid == 0) {
        float acc = b2[0];
#pragma unroll
        for (int u = 0; u < 10; ++u) acc = fmaf(sh_head[u], W2[u], acc);
        out[b] = acc + xb[(kT - 1) * kF];  // + x[b, 511, 0]
    }
}

extern "C" void kernel_launch(void* const* d_in, const int* in_sizes, int n_in,
                              void* d_out, int out_size, void* d_ws, size_t ws_size,
                              hipStream_t stream) {
    const float* x    = (const float*)d_in[0];
    const float* W_ih = (const float*)d_in[1];
    const float* W_hh = (const float*)d_in[2];
    const float* b_ih = (const float*)d_in[3];
    const float* b_hh = (const float*)d_in[4];
    const float* W1   = (const float*)d_in[5];
    const float* b1   = (const float*)d_in[6];
    const float* W2   = (const float*)d_in[7];
    const float* b2   = (const float*)d_in[8];
    float* out = (float*)d_out;

    lstm_fused<<<dim3(kB), dim3(256), 0, stream>>>(
        x, W_ih, W_hh, b_ih, b_hh, W1, b1, W2, b2, out);
}

// Round 2
// 564.310 us; speedup vs baseline: 1.0118x; 1.0118x over previous
//
#include <hip/hip_runtime.h>

// LSTM: B=1024, T=512, F=40, H=50, gates G=4H=200, fp32.
// One block per batch element; 512 sequential steps inside the block.
// Thread g owns gate-row g's weights in ARCH VGPRs: wih as 10x float4,
// whh as 26x float2 (row stride 200 B is only 8B-aligned).
// amdgpu_waves_per_eu(4,4) pins the register budget at 128 VGPR/wave so
// LLVM cannot squeeze to 64 and spill the weights (round-1 failure mode).

constexpr int kB = 1024;
constexpr int kT = 512;
constexpr int kF = 40;
constexpr int kH = 50;
constexpr int kG = 200;  // 4*H

__device__ __forceinline__ float fast_sigmoid(float v) {
    return __builtin_amdgcn_rcpf(1.f + __expf(-v));
}
__device__ __forceinline__ float fast_tanh(float v) {
    return 1.f - 2.f * __builtin_amdgcn_rcpf(__expf(2.f * v) + 1.f);
}

__global__ __attribute__((amdgpu_flat_work_group_size(256, 256),
                          amdgpu_waves_per_eu(4, 4)))
void lstm_fused(
    const float* __restrict__ x,      // [B,T,F]
    const float* __restrict__ W_ih,   // [G,F]
    const float* __restrict__ W_hh,   // [G,H]
    const float* __restrict__ b_ih,   // [G]
    const float* __restrict__ b_hh,   // [G]
    const float* __restrict__ W1,     // [10,H]
    const float* __restrict__ b1,     // [10]
    const float* __restrict__ W2,     // [1,10]
    const float* __restrict__ b2,     // [1]
    float* __restrict__ out)          // [B]
{
    const int b   = blockIdx.x;
    const int tid = threadIdx.x;

    __shared__ __align__(16) float sh_h[52];      // h state, padded to 13*float4
    __shared__ __align__(16) float sh_x[2][40];   // double-buffered x_t
    __shared__ __align__(16) float sh_pre[kG];    // gate pre-activations
    __shared__ float sh_head[10];

    // Per-thread weight registers (typed vectors to pin VGPR residency).
    float4 wih4[10];   // W_ih[g, 0:40]
    float2 whh2[26];   // W_hh[g, 0:50] + 2 zero pads
    float bias = 0.f;

    const float* __restrict__ xb = x + (size_t)b * kT * kF;

    if (tid < kG) {
        const float4* wr = (const float4*)(W_ih + tid * kF);   // 160B row, 16B aligned
#pragma unroll
        for (int q = 0; q < 10; ++q) wih4[q] = wr[q];
        const float2* hr = (const float2*)(W_hh + tid * kH);   // 200B row, 8B aligned
#pragma unroll
        for (int q = 0; q < 25; ++q) whh2[q] = hr[q];
        whh2[25] = make_float2(0.f, 0.f);
        bias = b_ih[tid] + b_hh[tid];
    }

    // init states: h0 = 0; c0 = 0 except c0[:,0] = 1
    if (tid < 52) sh_h[tid] = 0.f;
    float c = (tid == 0) ? 1.f : 0.f;

    // stage x[b,0,:]
    if (tid < 10) {
        ((float4*)sh_x[0])[tid] = ((const float4*)xb)[tid];
    }
    __syncthreads();

    float4 px = make_float4(0.f, 0.f, 0.f, 0.f);

    for (int t = 0; t < kT; ++t) {
        const int cur = t & 1;

        // prefetch x[b,t+1,:] into registers (lanes 200..209, wave 3)
        if (tid >= 200 && tid < 210 && (t + 1) < kT) {
            px = ((const float4*)(xb + (size_t)(t + 1) * kF))[tid - 200];
        }

        if (tid < kG) {
            float acc = bias;
            const float4* xv = (const float4*)sh_x[cur];
#pragma unroll
            for (int q = 0; q < 10; ++q) {          // F = 40 = 10*4
                float4 v = xv[q];                    // broadcast LDS read
                acc = fmaf(v.x, wih4[q].x, acc);
                acc = fmaf(v.y, wih4[q].y, acc);
                acc = fmaf(v.z, wih4[q].z, acc);
                acc = fmaf(v.w, wih4[q].w, acc);
            }
            const float4* hv = (const float4*)sh_h;
#pragma unroll
            for (int q = 0; q < 13; ++q) {          // H padded to 52 = 13*4
                float4 v = hv[q];                    // broadcast LDS read
                acc = fmaf(v.x, whh2[2 * q].x, acc);
                acc = fmaf(v.y, whh2[2 * q].y, acc);
                acc = fmaf(v.z, whh2[2 * q + 1].x, acc);
                acc = fmaf(v.w, whh2[2 * q + 1].y, acc);
            }
            sh_pre[tid] = acc;
        }
        __syncthreads();

        // cell update: thread j < 50 owns hidden unit j (c stays in register)
        if (tid < kH) {
            float gi = sh_pre[tid];
            float gf = sh_pre[tid + kH];
            float gg = sh_pre[tid + 2 * kH];
            float go = sh_pre[tid + 3 * kH];
            float i_s = fast_sigmoid(gi);
            float f_s = fast_sigmoid(gf);
            float o_s = fast_sigmoid(go);
            float g_t = fast_tanh(gg);
            c = fmaf(f_s, c, i_s * g_t);
            sh_h[tid] = o_s * fast_tanh(c);
        }
        // commit prefetched x into the other buffer
        if (tid >= 200 && tid < 210 && (t + 1) < kT) {
            ((float4*)sh_x[cur ^ 1])[tid - 200] = px;
        }
        __syncthreads();
    }

    // head: relu(h @ W1.T + b1) @ W2.T + b2 + x[b, T-1, 0]
    if (tid < 10) {
        float acc = b1[tid];
#pragma unroll
        for (int k = 0; k < kH; ++k) acc = fmaf(sh_h[k], W1[tid * kH + k], acc);
        sh_head[tid] = fmaxf(acc, 0.f);
    }
    __syncthreads();
    if (tid == 0) {
        float acc = b2[0];
#pragma unroll
        for (int u = 0; u < 10; ++u) acc = fmaf(sh_head[u], W2[u], acc);
        out[b] = acc + xb[(kT - 1) * kF];  // + x[b, 511, 0]
    }
}

extern "C" void kernel_launch(void* const* d_in, const int* in_sizes, int n_in,
                              void* d_out, int out_size, void* d_ws, size_t ws_size,
                              hipStream_t stream) {
    const float* x    = (const float*)d_in[0];
    const float* W_ih = (const float*)d_in[1];
    const float* W_hh = (const float*)d_in[2];
    const float* b_ih = (const float*)d_in[3];
    const float* b_hh = (const float*)d_in[4];
    const float* W1   = (const float*)d_in[5];
    const float* b1   = (const float*)d_in[6];
    const float* W2   = (const float*)d_in[7];
    const float* b2   = (const float*)d_in[8];
    float* out = (float*)d_out;

    lstm_fused<<<dim3(kB), dim3(256), 0, stream>>>(
        x, W_ih, W_hh, b_ih, b_hh, W1, b1, W2, b2, out);
}